// Round 1
// 90.098 us; speedup vs baseline: 1.0217x; 1.0217x over previous
//
#include <hip/hip_runtime.h>

typedef __attribute__((ext_vector_type(8))) short short8;
typedef __attribute__((ext_vector_type(4))) float f32x4;

#define TANH_SCALE 2.8853900817779268f  /* 2*log2(e): exp(2x) = exp2(x*TANH_SCALE) */
#define LOG_EPS   -18.420680743952367f  /* log(1e-8f): exact masked-out additive */
#define KC 128                           /* K-chunk staged through LDS */
#define LDP (KC + 8)                     /* LDS row stride (shorts): 16B-aligned rows,
                                            68 dwords -> uniform-optimal b128 banking */

static __device__ __forceinline__ unsigned short f2bf(float f) {
  unsigned u = __builtin_bit_cast(unsigned, f);
  u += 0x7FFFu + ((u >> 16) & 1u);   // round-to-nearest-even
  return (unsigned short)(u >> 16);
}
static __device__ __forceinline__ float bf2f(unsigned short h) {
  unsigned u = (unsigned)h << 16;
  return __builtin_bit_cast(float, u);
}

// Merged fp32->bf16 conversion + NT GEMM for both projections, exp2 epilogue.
// Per K-chunk: global fp32 -> registers -> (RNE cvt) -> LDS bf16 -> MFMA.
//   blocks [0,128):   decPt(256x1024) fp32 = exp2(c * W1 . dec^T)
//   blocks [128,384): encPb(8,256,256) bf16 = exp2(c * W2 . enc^T) per batch
// Block = 4 waves, block tile 64(M)x32(N); wave w: rows [64mt+16w,+16) x 32 cols.
// (unchanged from the 90.9us version -- kept as clean A/B control this round)
__global__ __launch_bounds__(256) void gemm_proj_cvt(
    const float* __restrict__ W1, const float* __restrict__ W2,
    const float* __restrict__ dec, const float* __restrict__ enc,
    float* __restrict__ decPt, unsigned short* __restrict__ encPb) {
  const int K = 512;
  int idx = blockIdx.x;
  const float *A, *Bp;
  int N, mt, nt;
  bool is_dec = (idx < 128);
  size_t cbase = 0;
  if (is_dec) {
    A = W1; Bp = dec; N = 1024;
    mt = idx >> 5; nt = idx & 31;
  } else {
    int j = idx - 128, z = j >> 5, rem = j & 31;
    A = W2; Bp = enc + (size_t)z * 256 * K; N = 256;
    mt = rem >> 3; nt = rem & 7;
    cbase = (size_t)z * 65536;
  }
  const int tid = threadIdx.x, wave = tid >> 6, lane = tid & 63;
  const int m0 = mt * 64;            // block-level A row base
  const int n0 = nt * 32;            // block-level B row base
  const int l16 = lane & 15, quad = lane >> 4, kb = quad * 8;

  __shared__ unsigned short lA[64][LDP];   // 17408 B
  __shared__ unsigned short lB[32][LDP];   //  8704 B

  f32x4 acc0 = {0.f,0.f,0.f,0.f}, acc1 = {0.f,0.f,0.f,0.f};

  // Staging: thread covers 8 A-float4 + 4 B-float4 per chunk.
  // f = i*256 + tid -> row = f>>5, c4 = f&31  (KC/4 = 32 float4 per row)
  float4 ra[8], rb[4];
#pragma unroll
  for (int i = 0; i < 8; ++i) {
    int f = i * 256 + tid, row = f >> 5, c4 = f & 31;
    ra[i] = *(const float4*)(A + (size_t)(m0 + row) * K + c4 * 4);
  }
#pragma unroll
  for (int i = 0; i < 4; ++i) {
    int f = i * 256 + tid, row = f >> 5, c4 = f & 31;
    rb[i] = *(const float4*)(Bp + (size_t)(n0 + row) * K + c4 * 4);
  }

#pragma unroll
  for (int kc = 0; kc < 4; ++kc) {
    // convert + write staged chunk to LDS
#pragma unroll
    for (int i = 0; i < 8; ++i) {
      int f = i * 256 + tid, row = f >> 5, c4 = f & 31;
      ushort4 o = { f2bf(ra[i].x), f2bf(ra[i].y), f2bf(ra[i].z), f2bf(ra[i].w) };
      *(ushort4*)&lA[row][c4 * 4] = o;
    }
#pragma unroll
    for (int i = 0; i < 4; ++i) {
      int f = i * 256 + tid, row = f >> 5, c4 = f & 31;
      ushort4 o = { f2bf(rb[i].x), f2bf(rb[i].y), f2bf(rb[i].z), f2bf(rb[i].w) };
      *(ushort4*)&lB[row][c4 * 4] = o;
    }
    __syncthreads();
    // prefetch next chunk (loads overlap the MFMAs below)
    if (kc < 3) {
      int k0n = (kc + 1) * KC;
#pragma unroll
      for (int i = 0; i < 8; ++i) {
        int f = i * 256 + tid, row = f >> 5, c4 = f & 31;
        ra[i] = *(const float4*)(A + (size_t)(m0 + row) * K + k0n + c4 * 4);
      }
#pragma unroll
      for (int i = 0; i < 4; ++i) {
        int f = i * 256 + tid, row = f >> 5, c4 = f & 31;
        rb[i] = *(const float4*)(Bp + (size_t)(n0 + row) * K + k0n + c4 * 4);
      }
    }
    // MFMA from LDS
#pragma unroll
    for (int ks = 0; ks < KC; ks += 32) {
      short8 a  = *(const short8*)&lA[wave * 16 + l16][ks + kb];
      short8 b0 = *(const short8*)&lB[l16][ks + kb];
      short8 b1 = *(const short8*)&lB[16 + l16][ks + kb];
      acc0 = __builtin_amdgcn_mfma_f32_16x16x32_bf16(a, b0, acc0, 0, 0, 0);
      acc1 = __builtin_amdgcn_mfma_f32_16x16x32_bf16(a, b1, acc1, 0, 0, 0);
    }
    __syncthreads();
  }

  // C/D layout: col = lane&15, row = quad*4 + reg. Store exp2(c*acc), coalesced in n.
  f32x4 accs[2] = {acc0, acc1};
  if (is_dec) {
#pragma unroll
    for (int j = 0; j < 2; ++j) {
      int n = n0 + j * 16 + l16;
#pragma unroll
      for (int r = 0; r < 4; ++r) {
        int m = m0 + wave * 16 + quad * 4 + r;
        decPt[(long)m * N + n] = __builtin_amdgcn_exp2f(accs[j][r] * TANH_SCALE);
      }
    }
  } else {
#pragma unroll
    for (int j = 0; j < 2; ++j) {
      int n = n0 + j * 16 + l16;
#pragma unroll
      for (int r = 0; r < 4; ++r) {
        int m = m0 + wave * 16 + quad * 4 + r;
        encPb[cbase + (long)m * N + n] =
            f2bf(__builtin_amdgcn_exp2f(accs[j][r] * TANH_SCALE));
      }
    }
  }
}

// Fused scores + masked log-softmax.
//   scores = -2 * sum_l vt[l] / (P[t][l]*E[s][l] + 1)  (+ softmax-invariant const, dropped)
// decPt: (L=256, BT=1024) fp32 transposed exp2-form; encPb: (B,L,S) bf16 exp2-form.
// Block = 1024 threads: s = tid&255, quarter q = tid>>8 does l in [64q, 64q+64).
// Block covers 4 consecutive t; epilogue: quarter q owns softmax of row t0+q.
// Grid = B*T/4 = 256 blocks x 16 waves -> 4 waves/SIMD, 1 block/CU.
//
// R0 change: 4-term common-denominator grouping. Since every a_i = 1+P_i*E_i >= 1,
//   sum_i v_i/a_i = (n01*d23 + n23*d01) / (d01*d23),
//   d01=a0*a1, n01=v0*a1+v1*a0 (and likewise 2,3)
// => 14 VALU + 1 rcp per 4 terms/t instead of 8 VALU + 4 rcp.
// v_rcp_f32 is quarter-rate (8 cyc/wave64): 3072 -> 2304 cyc/wave main loop (-25%).
// Overflow-safe: a_i <= ~2e4 (|proj| <= ~5 sigma), 4-product <= ~2e17 << fp32 max.
__global__ __launch_bounds__(1024) void fused_score_softmax(
    const float* __restrict__ decPt, const unsigned short* __restrict__ encPb,
    const float* __restrict__ mask, const float* __restrict__ vt,
    float* __restrict__ out) {
  const int T = 128, S = 256, L = 256;
  const int b = blockIdx.x >> 5;
  const int t0 = (blockIdx.x & 31) * 4;
  const int s = threadIdx.x & 255;
  const int q = threadIdx.x >> 8;
  const int l0 = q * (L / 4);

  const unsigned short* __restrict__ ep = encPb + (size_t)b * L * S + (size_t)l0 * S + s;
  const float* __restrict__ dp = decPt + (size_t)(b * T + t0) + (size_t)l0 * 1024;
  const float* __restrict__ vp = vt + l0;

  float acc0 = 0.f, acc1 = 0.f, acc2 = 0.f, acc3 = 0.f;
#pragma unroll 4
  for (int g = 0; g < 16; ++g) {
    const int l = g * 4;
    float e0 = bf2f(ep[(size_t)(l + 0) * S]);
    float e1 = bf2f(ep[(size_t)(l + 1) * S]);
    float e2 = bf2f(ep[(size_t)(l + 2) * S]);
    float e3 = bf2f(ep[(size_t)(l + 3) * S]);
    float4 P0 = *(const float4*)(dp + (size_t)(l + 0) * 1024);  // wave-uniform -> s_load
    float4 P1 = *(const float4*)(dp + (size_t)(l + 1) * 1024);
    float4 P2 = *(const float4*)(dp + (size_t)(l + 2) * 1024);
    float4 P3 = *(const float4*)(dp + (size_t)(l + 3) * 1024);
    float4 v  = *(const float4*)(vp + l);                       // wave-uniform -> s_load

#define TERM(ACC, C) {                                        \
    float a0 = fmaf(P0.C, e0, 1.0f);                          \
    float a1 = fmaf(P1.C, e1, 1.0f);                          \
    float a2 = fmaf(P2.C, e2, 1.0f);                          \
    float a3 = fmaf(P3.C, e3, 1.0f);                          \
    float d01 = a0 * a1, d23 = a2 * a3;                       \
    float n01 = fmaf(v.x, a1, v.y * a0);                      \
    float n23 = fmaf(v.z, a3, v.w * a2);                      \
    float d = d01 * d23;                                      \
    float n = fmaf(n01, d23, n23 * d01);                      \
    ACC = fmaf(n, __builtin_amdgcn_rcpf(d), ACC);             \
  }
    TERM(acc0, x)
    TERM(acc1, y)
    TERM(acc2, z)
    TERM(acc3, w)
#undef TERM
  }

  // combine l-quarters: everyone writes, then quarter q owns row t0+q
  __shared__ float partial[4][4][256];   // [quarter][t][s]
  partial[q][0][s] = acc0;
  partial[q][1][s] = acc1;
  partial[q][2][s] = acc2;
  partial[q][3][s] = acc3;
  __syncthreads();

  float lg = partial[0][q][s] + partial[1][q][s] + partial[2][q][s] + partial[3][q][s];

  // mask is exactly 0.0 or 1.0, and 1.0f + 1e-8f == 1.0f in fp32, so
  // log(mask+eps) == (mask != 0 ? 0 : log(1e-8f)) exactly.
  const float LN2 = 0.6931471805599453f, L2E = 1.4426950408889634f;
  {
    float m = mask[(size_t)(b * T + t0 + q) * S + s];
    lg = fmaf(-2.0f, lg, (m != 0.0f) ? 0.0f : LOG_EPS);
  }

  // softmax over s (256 wide = the 4 waves of this quarter)
  __shared__ float redm[16], reds[16];
  const int wid = threadIdx.x >> 6, lane = threadIdx.x & 63;

  float w = lg;
#pragma unroll
  for (int off = 1; off < 64; off <<= 1) w = fmaxf(w, __shfl_xor(w, off));
  if (lane == 0) redm[wid] = w;
  __syncthreads();
  float bm = fmaxf(fmaxf(redm[q * 4 + 0], redm[q * 4 + 1]),
                   fmaxf(redm[q * 4 + 2], redm[q * 4 + 3]));

  float e = __builtin_amdgcn_exp2f((lg - bm) * L2E);
#pragma unroll
  for (int off = 1; off < 64; off <<= 1) e += __shfl_xor(e, off);
  if (lane == 0) reds[wid] = e;
  __syncthreads();
  float sum = reds[q * 4 + 0] + reds[q * 4 + 1] + reds[q * 4 + 2] + reds[q * 4 + 3];

  out[(size_t)(b * T + t0 + q) * S + s] = lg - bm - LN2 * __builtin_amdgcn_logf(sum);
}

extern "C" void kernel_launch(void* const* d_in, const int* in_sizes, int n_in,
                              void* d_out, int out_size, void* d_ws, size_t ws_size,
                              hipStream_t stream) {
  const int B = 8, T = 128;
  const float* dec = (const float*)d_in[0];   // (8,128,512)
  const float* enc = (const float*)d_in[1];   // (8,256,512)
  const float* mask = (const float*)d_in[2];  // (8,128,256)
  const float* W1 = (const float*)d_in[3];    // (256,512)
  const float* W2 = (const float*)d_in[4];    // (256,512)
  const float* vt = (const float*)d_in[5];    // (256)
  float* out = (float*)d_out;                 // (8,128,256)

  char* ws = (char*)d_ws;
  float* decPt = (float*)(ws);                                // 1 MB (L x BT) fp32
  unsigned short* encPb = (unsigned short*)(ws + (1u << 20)); // 1 MB (B,L,S) bf16

  // 1) merged convert + both projections + exp2 epilogue (384 blocks, 1536 waves)
  gemm_proj_cvt<<<384, 256, 0, stream>>>(W1, W2, dec, enc, decPt, encPb);

  // 2) fused scores + masked log-softmax (256 blocks x 1024 threads, 4096 waves)
  fused_score_softmax<<<B * T / 4, 1024, 0, stream>>>(decPt, encPb, mask, vt, out);
  (void)in_sizes; (void)n_in; (void)out_size; (void)ws_size;
}